// Round 1
// baseline (12325.127 us; speedup 1.0000x reference)
//
#include <hip/hip_runtime.h>
#include <stdint.h>

#define T_STEPS 512
#define BATCH   64
#define DIM     512            // D == H == 512
#define NGROUP  4
#define WG_PER_GROUP 32
#define GB      16             // batch rows per group
#define TBH     (T_STEPS*BATCH*DIM)
#define BH      (BATCH*DIM)

typedef __attribute__((ext_vector_type(8))) short short8;
typedef __attribute__((ext_vector_type(4))) float f32x4;
typedef unsigned short u16;

__device__ __forceinline__ u16 f2bf(float f) {
  union { float f; uint32_t u; } c; c.f = f;
  uint32_t u = c.u;
  return (u16)((u + 0x7FFFu + ((u >> 16) & 1u)) >> 16);
}

// ---- pack w_ih|w_hh into per-wg bf16 MFMA B-fragment images -----------------
// image j (j=0..31): unit u = (gate w 0..3, ktile kt 0..31, lane 0..63), 8 bf16:
//   n = w*512 + j*16 + (lane&15);  k = kt*32 + 8*(lane>>4) + 0..7
//   k<512 -> w_ih[n][k], else w_hh[n][k-512]
__global__ void pack_w_kernel(const float* __restrict__ w_ih,
                              const float* __restrict__ w_hh,
                              uint4* __restrict__ wpack) {
  int j = blockIdx.x;
  for (int u = threadIdx.x; u < 8192; u += 256) {
    int w    = u >> 11;
    int kt   = (u >> 6) & 31;
    int lane = u & 63;
    int n  = w * 512 + j * 16 + (lane & 15);
    int k0 = kt * 32 + 8 * (lane >> 4);
    const float* src = (k0 < 512) ? (w_ih + (size_t)n * 512 + k0)
                                  : (w_hh + (size_t)n * 512 + (k0 - 512));
    uint32_t p0 = f2bf(src[0]) | ((uint32_t)f2bf(src[1]) << 16);
    uint32_t p1 = f2bf(src[2]) | ((uint32_t)f2bf(src[3]) << 16);
    uint32_t p2 = f2bf(src[4]) | ((uint32_t)f2bf(src[5]) << 16);
    uint32_t p3 = f2bf(src[6]) | ((uint32_t)f2bf(src[7]) << 16);
    wpack[(size_t)j * 8192 + u] = make_uint4(p0, p1, p2, p3);
  }
}

// ---- x (fp32) -> bf16, same [T][B][D] layout --------------------------------
__global__ void pack_x_kernel(const float* __restrict__ x, uint4* __restrict__ xbf) {
  size_t i = (size_t)blockIdx.x * 256 + threadIdx.x;     // unit of 8 elems
  const float4* src = (const float4*)x + i * 2;
  float4 a = src[0], b = src[1];
  uint32_t p0 = f2bf(a.x) | ((uint32_t)f2bf(a.y) << 16);
  uint32_t p1 = f2bf(a.z) | ((uint32_t)f2bf(a.w) << 16);
  uint32_t p2 = f2bf(b.x) | ((uint32_t)f2bf(b.y) << 16);
  uint32_t p3 = f2bf(b.z) | ((uint32_t)f2bf(b.w) << 16);
  xbf[i] = make_uint4(p0, p1, p2, p3);
}

// ---- persistent LSTM --------------------------------------------------------
__launch_bounds__(256, 1)
__global__ void lstm_persist(const float* __restrict__ h0, const float* __restrict__ c0,
                             const float* __restrict__ b_ih, const float* __restrict__ b_hh,
                             const uint4* __restrict__ wpack, const u16* __restrict__ xbf,
                             u16* __restrict__ h_buf, int* __restrict__ barrier_mem,
                             float* __restrict__ out) {
  __shared__ uint4 w_lds[8192];          // 128 KiB weights (fragment order)
  __shared__ float c_lds[4][16][16];     // gate staging [gate][batch][col]

  const int tid  = threadIdx.x;
  const int lane = tid & 63;
  const int wv   = tid >> 6;             // wave 0..3 == gate i,f,g,o
  const int wg   = blockIdx.x;
  const int grp  = wg >> 5;              // 0..3
  const int wgj  = wg & 31;              // 0..31 (column slice / weight image)
  const int B0   = grp * GB;

  for (int i = tid; i < 8192; i += 256) w_lds[i] = wpack[(size_t)wgj * 8192 + i];

  // pointwise mapping: thread -> (batch pb, col pc) of this wg's 16x16 h-slice
  const int pb   = tid >> 4;
  const int pc   = tid & 15;
  const int colg = wgj * 16 + pc;
  float c_reg = c0[(B0 + pb) * DIM + colg];
  const float bias0 = b_ih[0*512 + colg] + b_hh[0*512 + colg];
  const float bias1 = b_ih[1*512 + colg] + b_hh[1*512 + colg];
  const float bias2 = b_ih[2*512 + colg] + b_hh[2*512 + colg];
  const float bias3 = b_ih[3*512 + colg] + b_hh[3*512 + colg];

  // init h ping-pong parity 0
  h_buf[((0 * NGROUP + grp) * GB + pb) * DIM + colg] = f2bf(h0[(B0 + pb) * DIM + colg]);

  const int m  = lane & 15;              // A-fragment row (batch within group)
  const int kq = 8 * (lane >> 4);        // A/B-fragment k sub-offset

  int* cnt  = barrier_mem + grp * 64;
  int* flag = barrier_mem + grp * 64 + 32;
  int phase = 1;

  const short8* wl = (const short8*)w_lds;

  // x-part of step 0 gates (two accumulators for ILP)
  f32x4 xacc;
  {
    f32x4 a0 = (f32x4){0.f,0.f,0.f,0.f}, a1 = (f32x4){0.f,0.f,0.f,0.f};
    const u16* xrow = xbf + (size_t)(0 * BATCH + B0 + m) * DIM;
    for (int kt = 0; kt < 16; kt += 2) {
      short8 a = *((const short8*)(xrow + kt * 32 + kq));
      short8 b = wl[(wv * 32 + kt) * 64 + lane];
      a0 = __builtin_amdgcn_mfma_f32_16x16x32_bf16(a, b, a0, 0, 0, 0);
      short8 a2 = *((const short8*)(xrow + (kt + 1) * 32 + kq));
      short8 b2 = wl[(wv * 32 + kt + 1) * 64 + lane];
      a1 = __builtin_amdgcn_mfma_f32_16x16x32_bf16(a2, b2, a1, 0, 0, 0);
    }
    xacc = a0 + a1;
  }

  // ---- initial barrier: h0 slices visible group-wide ----
  __threadfence();
  __syncthreads();
  if (tid == 0) {
    int arrived = __hip_atomic_fetch_add(cnt, 1, __ATOMIC_ACQ_REL, __HIP_MEMORY_SCOPE_AGENT);
    if (arrived == WG_PER_GROUP * phase - 1)
      __hip_atomic_store(flag, phase, __ATOMIC_RELEASE, __HIP_MEMORY_SCOPE_AGENT);
    int spins = 0;
    while (__hip_atomic_load(flag, __ATOMIC_RELAXED, __HIP_MEMORY_SCOPE_AGENT) < phase) {
      __builtin_amdgcn_s_sleep(8);
      if (++spins > (1 << 16)) break;   // bailout: fail loud, never hang
    }
  }
  ++phase;
  __syncthreads();
  __threadfence();

  for (int t = 0; t < T_STEPS; ++t) {
    const int pr = t & 1;
    // h-part MFMAs (16 k-tiles), seeded with this step's x-part
    f32x4 acc0 = xacc, acc1 = (f32x4){0.f,0.f,0.f,0.f};
    const u16* hrow = h_buf + ((size_t)(pr * NGROUP + grp) * GB + m) * DIM;
    for (int kt = 0; kt < 16; kt += 2) {
      short8 a = *((const short8*)(hrow + kt * 32 + kq));
      short8 b = wl[(wv * 32 + 16 + kt) * 64 + lane];
      acc0 = __builtin_amdgcn_mfma_f32_16x16x32_bf16(a, b, acc0, 0, 0, 0);
      short8 a2 = *((const short8*)(hrow + (kt + 1) * 32 + kq));
      short8 b2 = wl[(wv * 32 + 16 + kt + 1) * 64 + lane];
      acc1 = __builtin_amdgcn_mfma_f32_16x16x32_bf16(a2, b2, acc1, 0, 0, 0);
    }
    f32x4 acc = acc0 + acc1;

    // stage C tile: C/D layout col=lane&15, row=(lane>>4)*4+reg (m89-verified)
    {
      int r0 = (lane >> 4) * 4;
      c_lds[wv][r0 + 0][lane & 15] = acc[0];
      c_lds[wv][r0 + 1][lane & 15] = acc[1];
      c_lds[wv][r0 + 2][lane & 15] = acc[2];
      c_lds[wv][r0 + 3][lane & 15] = acc[3];
    }
    __syncthreads();

    // pointwise LSTM cell (one thread per (batch,col))
    float gi = 1.f / (1.f + __expf(-(c_lds[0][pb][pc] + bias0)));
    float gf = 1.f / (1.f + __expf(-(c_lds[1][pb][pc] + bias1)));
    float gg = tanhf(c_lds[2][pb][pc] + bias2);
    float go = 1.f / (1.f + __expf(-(c_lds[3][pb][pc] + bias3)));
    c_reg = gf * c_reg + gi * gg;
    float h = go * tanhf(c_reg);

    h_buf[((size_t)((pr ^ 1) * NGROUP + grp) * GB + pb) * DIM + colg] = f2bf(h);
    out[((size_t)t * BATCH + B0 + pb) * DIM + colg] = h;
    if (t == T_STEPS - 1) {
      out[TBH + (B0 + pb) * DIM + colg]      = h;
      out[TBH + BH + (B0 + pb) * DIM + colg] = c_reg;
    }

    // publish h slice, then group barrier (monotonic counter)
    __threadfence();        // per-thread release: drain + wb L2 (agent scope)
    __syncthreads();
    if (tid == 0) {
      int arrived = __hip_atomic_fetch_add(cnt, 1, __ATOMIC_ACQ_REL, __HIP_MEMORY_SCOPE_AGENT);
      if (arrived == WG_PER_GROUP * phase - 1)
        __hip_atomic_store(flag, phase, __ATOMIC_RELEASE, __HIP_MEMORY_SCOPE_AGENT);
    }
    // overlap barrier propagation with next step's x-part (independent of h_t)
    if (t + 1 < T_STEPS) {
      f32x4 a0 = (f32x4){0.f,0.f,0.f,0.f}, a1 = (f32x4){0.f,0.f,0.f,0.f};
      const u16* xrow = xbf + (size_t)((t + 1) * BATCH + B0 + m) * DIM;
      for (int kt = 0; kt < 16; kt += 2) {
        short8 a = *((const short8*)(xrow + kt * 32 + kq));
        short8 b = wl[(wv * 32 + kt) * 64 + lane];
        a0 = __builtin_amdgcn_mfma_f32_16x16x32_bf16(a, b, a0, 0, 0, 0);
        short8 a2 = *((const short8*)(xrow + (kt + 1) * 32 + kq));
        short8 b2 = wl[(wv * 32 + kt + 1) * 64 + lane];
        a1 = __builtin_amdgcn_mfma_f32_16x16x32_bf16(a2, b2, a1, 0, 0, 0);
      }
      xacc = a0 + a1;
    }
    if (tid == 0) {
      int spins = 0;
      while (__hip_atomic_load(flag, __ATOMIC_RELAXED, __HIP_MEMORY_SCOPE_AGENT) < phase) {
        __builtin_amdgcn_s_sleep(8);
        if (++spins > (1 << 16)) break;
      }
    }
    ++phase;
    __syncthreads();
    __threadfence();        // per-thread acquire: invalidate L1/L2 before h reads
  }
}

extern "C" void kernel_launch(void* const* d_in, const int* in_sizes, int n_in,
                              void* d_out, int out_size, void* d_ws, size_t ws_size,
                              hipStream_t stream) {
  (void)in_sizes; (void)n_in; (void)out_size; (void)ws_size;
  const float* x    = (const float*)d_in[0];
  const float* h0   = (const float*)d_in[1];
  const float* c0   = (const float*)d_in[2];
  const float* w_ih = (const float*)d_in[3];
  const float* b_ih = (const float*)d_in[4];
  const float* w_hh = (const float*)d_in[5];
  const float* b_hh = (const float*)d_in[6];
  float* out = (float*)d_out;

  char* ws = (char*)d_ws;
  uint4* wpack = (uint4*)ws;                                    // 4 MiB
  u16*   xbf   = (u16*)(ws + ((size_t)4 << 20));                // 32 MiB
  u16*   hbuf  = (u16*)(ws + ((size_t)36 << 20));               // 128 KiB
  int*   bar   = (int*)(ws + ((size_t)36 << 20) + (128 << 10)); // 1 KiB

  hipMemsetAsync(bar, 0, 1024, stream);
  pack_w_kernel<<<dim3(32),   dim3(256), 0, stream>>>(w_ih, w_hh, wpack);
  pack_x_kernel<<<dim3(8192), dim3(256), 0, stream>>>(x, (uint4*)xbf);

  void* args[] = {(void*)&h0, (void*)&c0, (void*)&b_ih, (void*)&b_hh,
                  (void*)&wpack, (void*)&xbf, (void*)&hbuf, (void*)&bar, (void*)&out};
  hipError_t e = hipLaunchCooperativeKernel((void*)lstm_persist, dim3(NGROUP * WG_PER_GROUP),
                                            dim3(256), args, 0, stream);
  if (e != hipSuccess) {
    // fallback: 128 blocks @ 1 block/CU on 256 CUs will co-schedule
    lstm_persist<<<dim3(NGROUP * WG_PER_GROUP), dim3(256), 0, stream>>>(
        h0, c0, b_ih, b_hh, wpack, xbf, hbuf, bar, out);
  }
}

// Round 2
// 3780.004 us; speedup vs baseline: 3.2606x; 3.2606x over previous
//
#include <hip/hip_runtime.h>
#include <stdint.h>

#define T_STEPS 512
#define BATCH   64
#define DIM     512            // D == H == 512
#define NGROUP  4
#define WG_PER_GROUP 32
#define GB      16             // batch rows per group
#define TBH     (T_STEPS*BATCH*DIM)
#define BH      (BATCH*DIM)

typedef __attribute__((ext_vector_type(8))) short short8;
typedef __attribute__((ext_vector_type(4))) float f32x4;
typedef unsigned short u16;
typedef unsigned long long u64;

__device__ __forceinline__ u16 f2bf(float f) {
  union { float f; uint32_t u; } c; c.f = f;
  uint32_t u = c.u;
  return (u16)((u + 0x7FFFu + ((u >> 16) & 1u)) >> 16);
}

// ---- pack w_ih|w_hh into per-wg bf16 MFMA B-fragment images -----------------
// image j (j=0..31): unit u = (gate w 0..3, ktile kt 0..31, lane 0..63), 8 bf16:
//   n = w*512 + j*16 + (lane&15);  k = kt*32 + 8*(lane>>4) + 0..7
//   k<512 -> w_ih[n][k], else w_hh[n][k-512]
__global__ void pack_w_kernel(const float* __restrict__ w_ih,
                              const float* __restrict__ w_hh,
                              uint4* __restrict__ wpack) {
  int j = blockIdx.x;
  for (int u = threadIdx.x; u < 8192; u += 256) {
    int w    = u >> 11;
    int kt   = (u >> 6) & 31;
    int lane = u & 63;
    int n  = w * 512 + j * 16 + (lane & 15);
    int k0 = kt * 32 + 8 * (lane >> 4);
    const float* src = (k0 < 512) ? (w_ih + (size_t)n * 512 + k0)
                                  : (w_hh + (size_t)n * 512 + (k0 - 512));
    uint32_t p0 = f2bf(src[0]) | ((uint32_t)f2bf(src[1]) << 16);
    uint32_t p1 = f2bf(src[2]) | ((uint32_t)f2bf(src[3]) << 16);
    uint32_t p2 = f2bf(src[4]) | ((uint32_t)f2bf(src[5]) << 16);
    uint32_t p3 = f2bf(src[6]) | ((uint32_t)f2bf(src[7]) << 16);
    wpack[(size_t)j * 8192 + u] = make_uint4(p0, p1, p2, p3);
  }
}

// ---- x (fp32) -> bf16, same [T][B][D] layout --------------------------------
__global__ void pack_x_kernel(const float* __restrict__ x, uint4* __restrict__ xbf) {
  size_t i = (size_t)blockIdx.x * 256 + threadIdx.x;     // unit of 8 elems
  const float4* src = (const float4*)x + i * 2;
  float4 a = src[0], b = src[1];
  uint32_t p0 = f2bf(a.x) | ((uint32_t)f2bf(a.y) << 16);
  uint32_t p1 = f2bf(a.z) | ((uint32_t)f2bf(a.w) << 16);
  uint32_t p2 = f2bf(b.x) | ((uint32_t)f2bf(b.y) << 16);
  uint32_t p3 = f2bf(b.z) | ((uint32_t)f2bf(b.w) << 16);
  xbf[i] = make_uint4(p0, p1, p2, p3);
}

// wave0 polls all 32 wg-flags of its group with one 32-lane vector load.
// Flags are monotonic; stride 32 ints = 128 B (one line per flag).
__device__ __forceinline__ void group_wait(int* flags, int target) {
  int lane = threadIdx.x & 63;
  int* p = flags + (lane & 31) * 32;
  int spins = 0;
  for (;;) {
    int f = __hip_atomic_load(p, __ATOMIC_RELAXED, __HIP_MEMORY_SCOPE_AGENT);
    if (__ballot(f >= target) == ~0ull) break;
    if (++spins > (1 << 20)) break;     // bailout: wrong answer beats a hang
    __builtin_amdgcn_s_sleep(1);
  }
}

// ---- persistent LSTM --------------------------------------------------------
__launch_bounds__(256, 1)
__global__ void lstm_persist(const float* __restrict__ h0, const float* __restrict__ c0,
                             const float* __restrict__ b_ih, const float* __restrict__ b_hh,
                             const uint4* __restrict__ wpack, const u16* __restrict__ xbf,
                             u16* __restrict__ h_buf, int* __restrict__ barrier_mem,
                             float* __restrict__ out) {
  __shared__ uint4 w_lds[8192];          // 128 KiB weights (fragment order)
  __shared__ float c_lds[4][16][16];     // gate staging [gate][batch][col]

  const int tid  = threadIdx.x;
  const int lane = tid & 63;
  const int wv   = tid >> 6;             // wave 0..3 == gate i,f,g,o
  const int wg   = blockIdx.x;
  const int grp  = wg >> 5;              // 0..3
  const int wgj  = wg & 31;              // 0..31 (column slice / weight image)
  const int B0   = grp * GB;

  for (int i = tid; i < 8192; i += 256) w_lds[i] = wpack[(size_t)wgj * 8192 + i];

  // pointwise mapping: thread -> (batch pb, col pc) of this wg's 16x16 h-slice
  const int pb   = tid >> 4;
  const int pc   = tid & 15;
  const int colg = wgj * 16 + pc;
  float c_reg = c0[(B0 + pb) * DIM + colg];
  const float bias0 = b_ih[0*512 + colg] + b_hh[0*512 + colg];
  const float bias1 = b_ih[1*512 + colg] + b_hh[1*512 + colg];
  const float bias2 = b_ih[2*512 + colg] + b_hh[2*512 + colg];
  const float bias3 = b_ih[3*512 + colg] + b_hh[3*512 + colg];

  const int m   = lane & 15;             // A-fragment row (batch within group)
  const int kq  = 8 * (lane >> 4);       // k sub-offset (u16 units)
  const int kq8 = 2 * (lane >> 4);       // same in u64 units

  int* flags = barrier_mem + grp * 1024;
  const short8* wl = (const short8*)w_lds;

  // publish h0 slice (parity 0) via cache-bypassing agent stores (paired bf16)
  {
    float h0f = h0[(B0 + pb) * DIM + colg];
    float hn  = __shfl_xor(h0f, 1);
    if (!(colg & 1)) {
      uint32_t val = (uint32_t)f2bf(h0f) | ((uint32_t)f2bf(hn) << 16);
      uint32_t* p = (uint32_t*)(h_buf + ((size_t)(0 * NGROUP + grp) * GB + pb) * DIM + colg);
      __hip_atomic_store(p, val, __ATOMIC_RELAXED, __HIP_MEMORY_SCOPE_AGENT);
    }
  }

  // x-part of step 0 gates (two accumulators for ILP)
  f32x4 xacc;
  {
    f32x4 a0 = (f32x4){0.f,0.f,0.f,0.f}, a1 = (f32x4){0.f,0.f,0.f,0.f};
    const u16* xrow = xbf + (size_t)(0 * BATCH + B0 + m) * DIM;
    for (int kt = 0; kt < 16; kt += 2) {
      short8 a = *((const short8*)(xrow + kt * 32 + kq));
      short8 b = wl[(wv * 32 + kt) * 64 + lane];
      a0 = __builtin_amdgcn_mfma_f32_16x16x32_bf16(a, b, a0, 0, 0, 0);
      short8 a2 = *((const short8*)(xrow + (kt + 1) * 32 + kq));
      short8 b2 = wl[(wv * 32 + kt + 1) * 64 + lane];
      a1 = __builtin_amdgcn_mfma_f32_16x16x32_bf16(a2, b2, a1, 0, 0, 0);
    }
    xacc = a0 + a1;
  }

  // drain h0 stores to the coherence point, then publish flag, then wait group
  asm volatile("s_waitcnt vmcnt(0)" ::: "memory");
  __syncthreads();
  if (tid == 0)
    __hip_atomic_store(&flags[wgj * 32], 1, __ATOMIC_RELAXED, __HIP_MEMORY_SCOPE_AGENT);
  if (wv == 0) group_wait(flags, 1);
  __syncthreads();

  // load h A-fragments (parity 0) via cache-bypassing 8B agent loads
  u64 hq[32];
  {
    u64* h64 = (u64*)(h_buf + (size_t)(0 * NGROUP + grp) * GB * DIM);
    int base = m * 128 + kq8;            // 128 u64 per row
    #pragma unroll
    for (int kt = 0; kt < 16; ++kt) {
      hq[2*kt]   = __hip_atomic_load(&h64[base + kt*8],     __ATOMIC_RELAXED, __HIP_MEMORY_SCOPE_AGENT);
      hq[2*kt+1] = __hip_atomic_load(&h64[base + kt*8 + 1], __ATOMIC_RELAXED, __HIP_MEMORY_SCOPE_AGENT);
    }
  }

  for (int t = 0; t < T_STEPS; ++t) {
    const int pr = t & 1;

    // h-part MFMAs seeded with this step's x-part (A from hq regs, B from LDS)
    f32x4 acc0 = xacc, acc1 = (f32x4){0.f,0.f,0.f,0.f};
    #pragma unroll
    for (int kt = 0; kt < 16; kt += 2) {
      union { u64 q[2]; short8 s; } ua, ub;
      ua.q[0] = hq[2*kt];   ua.q[1] = hq[2*kt+1];
      short8 b = wl[(wv * 32 + 16 + kt) * 64 + lane];
      acc0 = __builtin_amdgcn_mfma_f32_16x16x32_bf16(ua.s, b, acc0, 0, 0, 0);
      ub.q[0] = hq[2*kt+2]; ub.q[1] = hq[2*kt+3];
      short8 b2 = wl[(wv * 32 + 16 + kt + 1) * 64 + lane];
      acc1 = __builtin_amdgcn_mfma_f32_16x16x32_bf16(ub.s, b2, acc1, 0, 0, 0);
    }
    f32x4 acc = acc0 + acc1;

    // stage C tile: C/D layout col=lane&15, row=(lane>>4)*4+reg (m89-verified)
    {
      int r0 = (lane >> 4) * 4;
      c_lds[wv][r0 + 0][lane & 15] = acc[0];
      c_lds[wv][r0 + 1][lane & 15] = acc[1];
      c_lds[wv][r0 + 2][lane & 15] = acc[2];
      c_lds[wv][r0 + 3][lane & 15] = acc[3];
    }
    __syncthreads();

    // pointwise LSTM cell (one thread per (batch,col))
    float gi = 1.f / (1.f + __expf(-(c_lds[0][pb][pc] + bias0)));
    float gf = 1.f / (1.f + __expf(-(c_lds[1][pb][pc] + bias1)));
    float gg = tanhf(c_lds[2][pb][pc] + bias2);
    float go = 1.f / (1.f + __expf(-(c_lds[3][pb][pc] + bias3)));
    c_reg = gf * c_reg + gi * gg;
    float h = go * tanhf(c_reg);

    // publish h_{t+1} slice (parity pr^1): paired bf16, agent-scope store
    {
      float hn = __shfl_xor(h, 1);
      if (!(colg & 1)) {
        uint32_t val = (uint32_t)f2bf(h) | ((uint32_t)f2bf(hn) << 16);
        uint32_t* p = (uint32_t*)(h_buf + ((size_t)((pr ^ 1) * NGROUP + grp) * GB + pb) * DIM + colg);
        __hip_atomic_store(p, val, __ATOMIC_RELAXED, __HIP_MEMORY_SCOPE_AGENT);
      }
    }

    // drain ONLY the h stores, then flag. out stores moved after the flag.
    asm volatile("s_waitcnt vmcnt(0)" ::: "memory");
    __syncthreads();
    if (tid == 0)
      __hip_atomic_store(&flags[wgj * 32], t + 2, __ATOMIC_RELAXED, __HIP_MEMORY_SCOPE_AGENT);

    // off-critical-path work while the flag propagates:
    out[((size_t)t * BATCH + B0 + pb) * DIM + colg] = h;   // normal cached store
    if (t == T_STEPS - 1) {
      out[TBH + (B0 + pb) * DIM + colg]      = h;
      out[TBH + BH + (B0 + pb) * DIM + colg] = c_reg;
    }

    if (t + 1 < T_STEPS) {
      // x-part of step t+1 (independent of h_{t+1}) — hides barrier latency
      {
        f32x4 a0 = (f32x4){0.f,0.f,0.f,0.f}, a1 = (f32x4){0.f,0.f,0.f,0.f};
        const u16* xrow = xbf + (size_t)((t + 1) * BATCH + B0 + m) * DIM;
        for (int kt = 0; kt < 16; kt += 2) {
          short8 a = *((const short8*)(xrow + kt * 32 + kq));
          short8 b = wl[(wv * 32 + kt) * 64 + lane];
          a0 = __builtin_amdgcn_mfma_f32_16x16x32_bf16(a, b, a0, 0, 0, 0);
          short8 a2 = *((const short8*)(xrow + (kt + 1) * 32 + kq));
          short8 b2 = wl[(wv * 32 + kt + 1) * 64 + lane];
          a1 = __builtin_amdgcn_mfma_f32_16x16x32_bf16(a2, b2, a1, 0, 0, 0);
        }
        xacc = a0 + a1;
      }
      if (wv == 0) group_wait(flags, t + 2);
      __syncthreads();
      // reload h A-fragments for next step (parity pr^1)
      u64* h64 = (u64*)(h_buf + (size_t)((pr ^ 1) * NGROUP + grp) * GB * DIM);
      int base = m * 128 + kq8;
      #pragma unroll
      for (int kt = 0; kt < 16; ++kt) {
        hq[2*kt]   = __hip_atomic_load(&h64[base + kt*8],     __ATOMIC_RELAXED, __HIP_MEMORY_SCOPE_AGENT);
        hq[2*kt+1] = __hip_atomic_load(&h64[base + kt*8 + 1], __ATOMIC_RELAXED, __HIP_MEMORY_SCOPE_AGENT);
      }
    }
  }
}

extern "C" void kernel_launch(void* const* d_in, const int* in_sizes, int n_in,
                              void* d_out, int out_size, void* d_ws, size_t ws_size,
                              hipStream_t stream) {
  (void)in_sizes; (void)n_in; (void)out_size; (void)ws_size;
  const float* x    = (const float*)d_in[0];
  const float* h0   = (const float*)d_in[1];
  const float* c0   = (const float*)d_in[2];
  const float* w_ih = (const float*)d_in[3];
  const float* b_ih = (const float*)d_in[4];
  const float* w_hh = (const float*)d_in[5];
  const float* b_hh = (const float*)d_in[6];
  float* out = (float*)d_out;

  char* ws = (char*)d_ws;
  uint4* wpack = (uint4*)ws;                                    // 4 MiB
  u16*   xbf   = (u16*)(ws + ((size_t)4 << 20));                // 32 MiB
  u16*   hbuf  = (u16*)(ws + ((size_t)36 << 20));               // 128 KiB
  int*   bar   = (int*)(ws + ((size_t)36 << 20) + (128 << 10)); // 16 KiB flags

  hipMemsetAsync(bar, 0, 16384, stream);
  pack_w_kernel<<<dim3(32),   dim3(256), 0, stream>>>(w_ih, w_hh, wpack);
  pack_x_kernel<<<dim3(8192), dim3(256), 0, stream>>>(x, (uint4*)xbf);

  void* args[] = {(void*)&h0, (void*)&c0, (void*)&b_ih, (void*)&b_hh,
                  (void*)&wpack, (void*)&xbf, (void*)&hbuf, (void*)&bar, (void*)&out};
  hipError_t e = hipLaunchCooperativeKernel((void*)lstm_persist, dim3(NGROUP * WG_PER_GROUP),
                                            dim3(256), args, 0, stream);
  if (e != hipSuccess) {
    // fallback: 128 blocks @ 1 block/CU on 256 CUs will co-schedule
    lstm_persist<<<dim3(NGROUP * WG_PER_GROUP), dim3(256), 0, stream>>>(
        h0, c0, b_ih, b_hh, wpack, xbf, hbuf, bar, out);
  }
}

// Round 4
// 2725.531 us; speedup vs baseline: 4.5221x; 1.3869x over previous
//
#include <hip/hip_runtime.h>
#include <stdint.h>

#define T_STEPS 512
#define BATCH   64
#define DIM     512            // D == H == 512
#define NGROUP  4
#define WG_PER_GROUP 32
#define GB      16             // batch rows per group
#define TBH     (T_STEPS*BATCH*DIM)
#define BH      (BATCH*DIM)

typedef __attribute__((ext_vector_type(8))) short short8;
typedef __attribute__((ext_vector_type(4))) float f32x4;
typedef __attribute__((ext_vector_type(4))) unsigned int u32x4;
typedef unsigned short u16;
typedef unsigned long long u64;

__device__ __forceinline__ u16 f2bf(float f) {
  union { float f; uint32_t u; } c; c.f = f;
  uint32_t u = c.u;
  return (u16)((u + 0x7FFFu + ((u >> 16) & 1u)) >> 16);
}

__device__ __forceinline__ float fsigmoid(float x) {
  float e = __expf(-x);
  return __builtin_amdgcn_rcpf(1.f + e);
}
__device__ __forceinline__ float ftanh(float x) {
  float e = __expf(2.f * x);           // +inf -> rcp 0 -> 1 ; 0 -> -1 : graceful
  return 1.f - 2.f * __builtin_amdgcn_rcpf(e + 1.f);
}

// ---- pack w_ih|w_hh into per-wg bf16 MFMA B-fragment images -----------------
// image j (j=0..31): unit u = (gate w 0..3, ktile kt 0..31, lane 0..63), 8 bf16:
//   n = w*512 + j*16 + (lane&15);  k = kt*32 + 8*(lane>>4) + 0..7
//   k<512 -> w_ih[n][k], else w_hh[n][k-512]
__global__ void pack_w_kernel(const float* __restrict__ w_ih,
                              const float* __restrict__ w_hh,
                              uint4* __restrict__ wpack) {
  int j = blockIdx.x;
  for (int u = threadIdx.x; u < 8192; u += 256) {
    int w    = u >> 11;
    int kt   = (u >> 6) & 31;
    int lane = u & 63;
    int n  = w * 512 + j * 16 + (lane & 15);
    int k0 = kt * 32 + 8 * (lane >> 4);
    const float* src = (k0 < 512) ? (w_ih + (size_t)n * 512 + k0)
                                  : (w_hh + (size_t)n * 512 + (k0 - 512));
    uint32_t p0 = f2bf(src[0]) | ((uint32_t)f2bf(src[1]) << 16);
    uint32_t p1 = f2bf(src[2]) | ((uint32_t)f2bf(src[3]) << 16);
    uint32_t p2 = f2bf(src[4]) | ((uint32_t)f2bf(src[5]) << 16);
    uint32_t p3 = f2bf(src[6]) | ((uint32_t)f2bf(src[7]) << 16);
    wpack[(size_t)j * 8192 + u] = make_uint4(p0, p1, p2, p3);
  }
}

// ---- x (fp32) -> bf16, same [T][B][D] layout --------------------------------
__global__ void pack_x_kernel(const float* __restrict__ x, uint4* __restrict__ xbf) {
  size_t i = (size_t)blockIdx.x * 256 + threadIdx.x;     // unit of 8 elems
  const float4* src = (const float4*)x + i * 2;
  float4 a = src[0], b = src[1];
  uint32_t p0 = f2bf(a.x) | ((uint32_t)f2bf(a.y) << 16);
  uint32_t p1 = f2bf(a.z) | ((uint32_t)f2bf(a.w) << 16);
  uint32_t p2 = f2bf(b.x) | ((uint32_t)f2bf(b.y) << 16);
  uint32_t p3 = f2bf(b.z) | ((uint32_t)f2bf(b.w) << 16);
  xbf[i] = make_uint4(p0, p1, p2, p3);
}

// ---- zero the sentinel rows (row 0 of every tile, both parities) ------------
// Runs stream-ordered BEFORE lstm_persist: establishes a known LSB=0 state for
// all sentinel words every launch (graph replays re-poison ws via the cached
// path, which bypass readers may not see; this kernel writes via bypass).
__global__ void init_h_kernel(u16* __restrict__ h_buf) {
  int i = threadIdx.x + blockIdx.x * 256;  // 0..2047 u32 words
  int row = i >> 8;                        // 0..7 : p*4+g
  int off = i & 255;
  int p = row >> 2, g = row & 3;
  uint32_t* dst = (uint32_t*)(h_buf + (size_t)(p * NGROUP + g) * GB * DIM) + off;
  __hip_atomic_store(dst, 0u, __ATOMIC_RELAXED, __HIP_MEMORY_SCOPE_AGENT);
}

// ---- persistent LSTM --------------------------------------------------------
// Exchange protocol (per group, per step):
//   producer: store h rows 1..15 (bypass) -> __syncthreads (vmcnt drain) ->
//             store row 0 with every bf16 LSB forced to tag_w(t).
//   consumer: poll row 0 (16B/lane bypass) until all LSBs == e(t); then load
//             full tile once (phase-2, issued strictly after the poll branch).
// Tags: tag_w(t) = 1 ^ (((t+1)>>1)&1)  (h0 uses t=-1 -> 1); e(t) = 1 ^ ((t>>1)&1).
// Each buffer's write sequence alternates tags, first write = 1, pre-state = 0.
__launch_bounds__(256, 1)
__global__ void lstm_persist(const float* __restrict__ h0, const float* __restrict__ c0,
                             const float* __restrict__ b_ih, const float* __restrict__ b_hh,
                             const uint4* __restrict__ wpack, const u16* __restrict__ xbf,
                             u16* __restrict__ h_buf, float* __restrict__ out) {
  __shared__ uint4 w_lds[8192];          // 128 KiB weights (fragment order)
  __shared__ float c_lds[4][16][16];     // gate staging [gate][batch][col]

  const int tid  = threadIdx.x;
  const int lane = tid & 63;
  const int wv   = tid >> 6;             // wave 0..3 == gate i,f,g,o
  const int wg   = blockIdx.x;
  const int grp  = wg >> 5;              // 0..3
  const int wgj  = wg & 31;              // 0..31 (column slice / weight image)
  const int B0   = grp * GB;

  for (int i = tid; i < 8192; i += 256) w_lds[i] = wpack[(size_t)wgj * 8192 + i];

  const int pb   = tid >> 4;             // pointwise batch row
  const int pc   = tid & 15;             // pointwise col
  const int colg = wgj * 16 + pc;
  float c_reg = c0[(B0 + pb) * DIM + colg];
  const float bias0 = b_ih[0*512 + colg] + b_hh[0*512 + colg];
  const float bias1 = b_ih[1*512 + colg] + b_hh[1*512 + colg];
  const float bias2 = b_ih[2*512 + colg] + b_hh[2*512 + colg];
  const float bias3 = b_ih[3*512 + colg] + b_hh[3*512 + colg];

  const int m  = lane & 15;              // A-fragment row
  const int kq = 8 * (lane >> 4);        // k sub-offset (u16 units)

  const short8* wl = (const short8*)w_lds;

  __syncthreads();                       // w_lds ready before ANY wl read

  // publish h0 rows 1..15 (parity 0), bypass stores
  {
    float h0f = h0[(B0 + pb) * DIM + colg];
    float h0n = __shfl_xor(h0f, 1);
    uint32_t both = (uint32_t)f2bf(h0f) | ((uint32_t)f2bf(h0n) << 16);
    if (pb != 0 && !(pc & 1)) {
      uint32_t* p = (uint32_t*)(h_buf + ((size_t)(0 * NGROUP + grp) * GB + pb) * DIM + colg);
      __hip_atomic_store(p, both, __ATOMIC_RELAXED, __HIP_MEMORY_SCOPE_AGENT);
    }
    // x-part of step 0 (overlaps the store drain)
    f32x4 a0 = (f32x4){0.f,0.f,0.f,0.f}, a1 = (f32x4){0.f,0.f,0.f,0.f};
    const u16* xrow = xbf + (size_t)(0 * BATCH + B0 + m) * DIM;
    for (int kt = 0; kt < 16; kt += 2) {
      short8 a = *((const short8*)(xrow + kt * 32 + kq));
      a0 = __builtin_amdgcn_mfma_f32_16x16x32_bf16(a, wl[(wv*32+kt)*64+lane], a0, 0,0,0);
      short8 a2 = *((const short8*)(xrow + (kt+1) * 32 + kq));
      a1 = __builtin_amdgcn_mfma_f32_16x16x32_bf16(a2, wl[(wv*32+kt+1)*64+lane], a1, 0,0,0);
    }
    f32x4 xa = a0 + a1;

    __syncthreads();                     // drains rows 1..15 (vmcnt(0) before barrier)
    if (pb == 0 && !(pc & 1)) {          // sentinel row, tag = 1
      uint32_t v = (both & 0xFFFEFFFEu) | 0x00010001u;
      uint32_t* p = (uint32_t*)(h_buf + (size_t)(0 * NGROUP + grp) * GB * DIM + colg);
      __hip_atomic_store(p, v, __ATOMIC_RELAXED, __HIP_MEMORY_SCOPE_AGENT);
    }

    // main loop
    f32x4 xacc = xa;
    for (int t = 0; t < T_STEPS; ++t) {
      const int pr = t & 1;
      const u16* tb = h_buf + (size_t)(pr * NGROUP + grp) * GB * DIM;
      const uint32_t e = 1u ^ (((uint32_t)t >> 1) & 1u);
      const uint32_t want = e ? 0x00010001u : 0u;

      // ---- phase 1: poll sentinel row (1 KiB, 16B/lane) ----
      {
        uint64_t pa1 = (uint64_t)tb + (uint64_t)lane * 16;
        int spins = 0;
        for (;;) {
          u32x4 s;
          asm volatile("global_load_dwordx4 %0, %1, off sc0 sc1"
                       : "=v"(s) : "v"(pa1) : "memory");
          asm volatile("s_waitcnt vmcnt(0)" ::: "memory");
          __builtin_amdgcn_sched_barrier(0);
          uint32_t andv = s.x & s.y & s.z & s.w;
          uint32_t orv  = s.x | s.y | s.z | s.w;
          uint32_t chk  = e ? (andv & 0x00010001u) : (orv & 0x00010001u);
          if (__ballot(chk == want) == ~0ull) break;
          if (++spins > (1 << 18)) break;      // fail loud, never hang
        }
      }

      // ---- phase 2: load full A-fragment tile (issued after poll branch) ----
      union HU { u32x4 u; short8 s; } hq[16];
      {
        uint64_t pa2 = (uint64_t)tb + (uint64_t)(m * 1024 + (lane >> 4) * 16);
#define HLOAD(i, lit)                                                          \
        asm volatile("global_load_dwordx4 %0, %1, off offset:" lit " sc0 sc1"  \
                     : "=v"(hq[i].u) : "v"(pa2) : "memory");
        HLOAD(0,"0")    HLOAD(1,"64")   HLOAD(2,"128")  HLOAD(3,"192")
        HLOAD(4,"256")  HLOAD(5,"320")  HLOAD(6,"384")  HLOAD(7,"448")
        HLOAD(8,"512")  HLOAD(9,"576")  HLOAD(10,"640") HLOAD(11,"704")
        HLOAD(12,"768") HLOAD(13,"832") HLOAD(14,"896") HLOAD(15,"960")
#undef HLOAD
        asm volatile("s_waitcnt vmcnt(0)" ::: "memory");
        __builtin_amdgcn_sched_barrier(0);
      }

      // ---- h-part MFMAs seeded with this step's x-part ----
      f32x4 acc0 = xacc, acc1 = (f32x4){0.f,0.f,0.f,0.f};
      #pragma unroll
      for (int kt = 0; kt < 16; kt += 2) {
        acc0 = __builtin_amdgcn_mfma_f32_16x16x32_bf16(hq[kt].s,   wl[(wv*32+16+kt)*64+lane],   acc0, 0,0,0);
        acc1 = __builtin_amdgcn_mfma_f32_16x16x32_bf16(hq[kt+1].s, wl[(wv*32+16+kt+1)*64+lane], acc1, 0,0,0);
      }
      f32x4 acc = acc0 + acc1;

      // stage C tile: C/D layout col=lane&15, row=(lane>>4)*4+reg (m89-verified)
      {
        int r0 = (lane >> 4) * 4;
        c_lds[wv][r0 + 0][lane & 15] = acc[0];
        c_lds[wv][r0 + 1][lane & 15] = acc[1];
        c_lds[wv][r0 + 2][lane & 15] = acc[2];
        c_lds[wv][r0 + 3][lane & 15] = acc[3];
      }
      __syncthreads();

      // pointwise LSTM cell
      float gi = fsigmoid(c_lds[0][pb][pc] + bias0);
      float gf = fsigmoid(c_lds[1][pb][pc] + bias1);
      float gg = ftanh  (c_lds[2][pb][pc] + bias2);
      float go = fsigmoid(c_lds[3][pb][pc] + bias3);
      c_reg = gf * c_reg + gi * gg;
      float h = go * ftanh(c_reg);

      if (t < T_STEPS - 1) {
        // publish h_{t+1} rows 1..15 into parity pr^1
        float hn = __shfl_xor(h, 1);
        uint32_t both = (uint32_t)f2bf(h) | ((uint32_t)f2bf(hn) << 16);
        if (pb != 0 && !(pc & 1)) {
          uint32_t* p = (uint32_t*)(h_buf + ((size_t)((pr ^ 1) * NGROUP + grp) * GB + pb) * DIM + colg);
          __hip_atomic_store(p, both, __ATOMIC_RELAXED, __HIP_MEMORY_SCOPE_AGENT);
        }
        __syncthreads();                 // drain rows 1..15 + protect c_lds reuse
        {
          const uint32_t tagw = 1u ^ ((((uint32_t)t + 1) >> 1) & 1u);
          if (pb == 0 && !(pc & 1)) {
            uint32_t v = (both & 0xFFFEFFFEu) | (tagw * 0x00010001u);
            uint32_t* p = (uint32_t*)(h_buf + (size_t)((pr ^ 1) * NGROUP + grp) * GB * DIM + colg);
            __hip_atomic_store(p, v, __ATOMIC_RELAXED, __HIP_MEMORY_SCOPE_AGENT);
          }
        }
        // off-critical-path: output store + next step's x-part (overlaps sentinel flight)
        out[((size_t)t * BATCH + B0 + pb) * DIM + colg] = h;
        f32x4 a2_0 = (f32x4){0.f,0.f,0.f,0.f}, a2_1 = (f32x4){0.f,0.f,0.f,0.f};
        const u16* xr = xbf + (size_t)((t + 1) * BATCH + B0 + m) * DIM;
        for (int kt = 0; kt < 16; kt += 2) {
          short8 a = *((const short8*)(xr + kt * 32 + kq));
          a2_0 = __builtin_amdgcn_mfma_f32_16x16x32_bf16(a, wl[(wv*32+kt)*64+lane], a2_0, 0,0,0);
          short8 a2 = *((const short8*)(xr + (kt+1) * 32 + kq));
          a2_1 = __builtin_amdgcn_mfma_f32_16x16x32_bf16(a2, wl[(wv*32+kt+1)*64+lane], a2_1, 0,0,0);
        }
        xacc = a2_0 + a2_1;
      } else {
        out[((size_t)t * BATCH + B0 + pb) * DIM + colg] = h;
        out[TBH + (B0 + pb) * DIM + colg]      = h;
        out[TBH + BH + (B0 + pb) * DIM + colg] = c_reg;
      }
    }
  }
}

extern "C" void kernel_launch(void* const* d_in, const int* in_sizes, int n_in,
                              void* d_out, int out_size, void* d_ws, size_t ws_size,
                              hipStream_t stream) {
  (void)in_sizes; (void)n_in; (void)out_size; (void)ws_size;
  const float* x    = (const float*)d_in[0];
  const float* h0   = (const float*)d_in[1];
  const float* c0   = (const float*)d_in[2];
  const float* w_ih = (const float*)d_in[3];
  const float* b_ih = (const float*)d_in[4];
  const float* w_hh = (const float*)d_in[5];
  const float* b_hh = (const float*)d_in[6];
  float* out = (float*)d_out;

  char* ws = (char*)d_ws;
  uint4* wpack = (uint4*)ws;                                    // 4 MiB
  u16*   xbf   = (u16*)(ws + ((size_t)4 << 20));                // 32 MiB
  u16*   hbuf  = (u16*)(ws + ((size_t)36 << 20));               // 128 KiB

  pack_w_kernel<<<dim3(32),   dim3(256), 0, stream>>>(w_ih, w_hh, wpack);
  pack_x_kernel<<<dim3(8192), dim3(256), 0, stream>>>(x, (uint4*)xbf);
  init_h_kernel<<<dim3(8),    dim3(256), 0, stream>>>(hbuf);

  void* args[] = {(void*)&h0, (void*)&c0, (void*)&b_ih, (void*)&b_hh,
                  (void*)&wpack, (void*)&xbf, (void*)&hbuf, (void*)&out};
  hipError_t e = hipLaunchCooperativeKernel((void*)lstm_persist, dim3(NGROUP * WG_PER_GROUP),
                                            dim3(256), args, 0, stream);
  if (e != hipSuccess) {
    // fallback: 128 blocks @ 1 block/CU on 256 CUs will co-schedule
    lstm_persist<<<dim3(NGROUP * WG_PER_GROUP), dim3(256), 0, stream>>>(
        h0, c0, b_ih, b_hh, wpack, xbf, hbuf, out);
  }
}

// Round 5
// 2656.506 us; speedup vs baseline: 4.6396x; 1.0260x over previous
//
#include <hip/hip_runtime.h>
#include <stdint.h>

#define T_STEPS 512
#define BATCH   64
#define DIM     512            // D == H == 512
#define NGROUP  4
#define WG_PER_GROUP 32
#define GB      16             // batch rows per group
#define TBH     (T_STEPS*BATCH*DIM)
#define BH      (BATCH*DIM)
#define TAGM    0x00010001u

typedef __attribute__((ext_vector_type(8))) short short8;
typedef __attribute__((ext_vector_type(4))) float f32x4;
typedef __attribute__((ext_vector_type(4))) unsigned int u32x4;
typedef unsigned short u16;

__device__ __forceinline__ u16 f2bf(float f) {
  union { float f; uint32_t u; } c; c.f = f;
  uint32_t u = c.u;
  return (u16)((u + 0x7FFFu + ((u >> 16) & 1u)) >> 16);
}

__device__ __forceinline__ float fsigmoid(float x) {
  float e = __expf(-x);
  return __builtin_amdgcn_rcpf(1.f + e);
}
__device__ __forceinline__ float ftanh(float x) {
  float e = __expf(2.f * x);
  return 1.f - 2.f * __builtin_amdgcn_rcpf(e + 1.f);
}

// ---- pack w_ih|w_hh into per-wg bf16 MFMA B-fragment images -----------------
// image j (j=0..31): unit u = (gate w 0..3, ktile kt 0..31, lane 0..63), 8 bf16:
//   n = w*512 + j*16 + (lane&15);  k = kt*32 + 8*(lane>>4) + 0..7
//   k<512 -> w_ih[n][k], else w_hh[n][k-512]
__global__ void pack_w_kernel(const float* __restrict__ w_ih,
                              const float* __restrict__ w_hh,
                              uint4* __restrict__ wpack) {
  int j = blockIdx.x;
  for (int u = threadIdx.x; u < 8192; u += 256) {
    int w    = u >> 11;
    int kt   = (u >> 6) & 31;
    int lane = u & 63;
    int n  = w * 512 + j * 16 + (lane & 15);
    int k0 = kt * 32 + 8 * (lane >> 4);
    const float* src = (k0 < 512) ? (w_ih + (size_t)n * 512 + k0)
                                  : (w_hh + (size_t)n * 512 + (k0 - 512));
    uint32_t p0 = f2bf(src[0]) | ((uint32_t)f2bf(src[1]) << 16);
    uint32_t p1 = f2bf(src[2]) | ((uint32_t)f2bf(src[3]) << 16);
    uint32_t p2 = f2bf(src[4]) | ((uint32_t)f2bf(src[5]) << 16);
    uint32_t p3 = f2bf(src[6]) | ((uint32_t)f2bf(src[7]) << 16);
    wpack[(size_t)j * 8192 + u] = make_uint4(p0, p1, p2, p3);
  }
}

// ---- x (fp32) -> bf16, same [T][B][D] layout --------------------------------
__global__ void pack_x_kernel(const float* __restrict__ x, uint4* __restrict__ xbf) {
  size_t i = (size_t)blockIdx.x * 256 + threadIdx.x;     // unit of 8 elems
  const float4* src = (const float4*)x + i * 2;
  float4 a = src[0], b = src[1];
  uint32_t p0 = f2bf(a.x) | ((uint32_t)f2bf(a.y) << 16);
  uint32_t p1 = f2bf(a.z) | ((uint32_t)f2bf(a.w) << 16);
  uint32_t p2 = f2bf(b.x) | ((uint32_t)f2bf(b.y) << 16);
  uint32_t p3 = f2bf(b.z) | ((uint32_t)f2bf(b.w) << 16);
  xbf[i] = make_uint4(p0, p1, p2, p3);
}

// ---- persistent LSTM --------------------------------------------------------
// Exchange protocol (per group, per step): EVERY bf16 of the h-tile carries a
// tag in its LSB. Producer fires tagged stores (no ordering needed: u32 stores
// are atomic, partially-visible lines show stale tags word-wise). Consumer
// retry-loads the full tile and validates all tags — the poll IS the load.
// Tags: write at step t uses tag_w = 1^(((t+1)>>1)&1) (h0: tag 1);
// reader at step t expects e = 1^((t>>1)&1). Per-buffer sequence alternates
// 1,0,1,0 (stale gen always mismatches); pre-first state (0xAA poison -> LSB 0,
// or prior run's end state -> tag 0) only read at t=0,1 where 1 is expected.
__launch_bounds__(256, 1)
__global__ void lstm_persist(const float* __restrict__ h0, const float* __restrict__ c0,
                             const float* __restrict__ b_ih, const float* __restrict__ b_hh,
                             const uint4* __restrict__ wpack, const u16* __restrict__ xbf,
                             u16* __restrict__ h_buf, float* __restrict__ out) {
  __shared__ uint4 w_lds[8192];          // 128 KiB weights (fragment order)
  __shared__ float c_lds[4][16][16];     // gate staging [gate][batch][col]

  const int tid  = threadIdx.x;
  const int lane = tid & 63;
  const int wv   = tid >> 6;             // wave 0..3 == gate i,f,g,o
  const int wg   = blockIdx.x;
  const int grp  = wg >> 5;              // 0..3
  const int wgj  = wg & 31;              // 0..31 (column slice / weight image)
  const int B0   = grp * GB;

  for (int i = tid; i < 8192; i += 256) w_lds[i] = wpack[(size_t)wgj * 8192 + i];

  const int pb   = tid >> 4;             // pointwise batch row
  const int pc   = tid & 15;             // pointwise col
  const int colg = wgj * 16 + pc;
  float c_reg = c0[(B0 + pb) * DIM + colg];
  const float bias0 = b_ih[0*512 + colg] + b_hh[0*512 + colg];
  const float bias1 = b_ih[1*512 + colg] + b_hh[1*512 + colg];
  const float bias2 = b_ih[2*512 + colg] + b_hh[2*512 + colg];
  const float bias3 = b_ih[3*512 + colg] + b_hh[3*512 + colg];

  const int m  = lane & 15;              // A-fragment row
  const int kq = 8 * (lane >> 4);        // k sub-offset (u16 units)

  const short8* wl = (const short8*)w_lds;

  __syncthreads();                       // w_lds ready before ANY wl read

  // publish h0 (parity 0), every word tagged with 1
  {
    float h0f = h0[(B0 + pb) * DIM + colg];
    float h0n = __shfl_xor(h0f, 1);
    if (!(pc & 1)) {
      uint32_t both = (uint32_t)f2bf(h0f) | ((uint32_t)f2bf(h0n) << 16);
      uint32_t v = (both & ~TAGM) | TAGM;
      uint32_t* p = (uint32_t*)(h_buf + ((size_t)(0 * NGROUP + grp) * GB + pb) * DIM + colg);
      __hip_atomic_store(p, v, __ATOMIC_RELAXED, __HIP_MEMORY_SCOPE_AGENT);
    }
  }

  // x-part of step 0 (overlaps the h0 store flight)
  f32x4 xacc;
  {
    f32x4 a0 = (f32x4){0.f,0.f,0.f,0.f}, a1 = (f32x4){0.f,0.f,0.f,0.f};
    const u16* xrow = xbf + (size_t)(0 * BATCH + B0 + m) * DIM;
    for (int kt = 0; kt < 16; kt += 2) {
      short8 a = *((const short8*)(xrow + kt * 32 + kq));
      a0 = __builtin_amdgcn_mfma_f32_16x16x32_bf16(a, wl[(wv*32+kt)*64+lane], a0, 0,0,0);
      short8 a2 = *((const short8*)(xrow + (kt+1) * 32 + kq));
      a1 = __builtin_amdgcn_mfma_f32_16x16x32_bf16(a2, wl[(wv*32+kt+1)*64+lane], a1, 0,0,0);
    }
    xacc = a0 + a1;
  }

  for (int t = 0; t < T_STEPS; ++t) {
    const int pr = t & 1;
    const u16* tb = h_buf + (size_t)(pr * NGROUP + grp) * GB * DIM;
    const uint32_t e = 1u ^ (((uint32_t)t >> 1) & 1u);

    // ---- merged poll+load: retry full tile until every word's tag == e ----
    union HU { u32x4 u; short8 s; } hq[16];
    {
      uint64_t pa2 = (uint64_t)tb + (uint64_t)(m * 1024 + (lane >> 4) * 16);
      int spins = 0;
      for (;;) {
#define HLOAD(i, lit)                                                          \
        asm volatile("global_load_dwordx4 %0, %1, off offset:" lit " sc0 sc1"  \
                     : "=v"(hq[i].u) : "v"(pa2) : "memory");
        HLOAD(0,"0")    HLOAD(1,"64")   HLOAD(2,"128")  HLOAD(3,"192")
        HLOAD(4,"256")  HLOAD(5,"320")  HLOAD(6,"384")  HLOAD(7,"448")
        HLOAD(8,"512")  HLOAD(9,"576")  HLOAD(10,"640") HLOAD(11,"704")
        HLOAD(12,"768") HLOAD(13,"832") HLOAD(14,"896") HLOAD(15,"960")
#undef HLOAD
        asm volatile("s_waitcnt vmcnt(0)" ::: "memory");
        __builtin_amdgcn_sched_barrier(0);
        uint32_t andv = 0xFFFFFFFFu, orv = 0u;
        #pragma unroll
        for (int i = 0; i < 16; ++i) {
          u32x4 v = hq[i].u;
          andv &= v.x & v.y & v.z & v.w;
          orv  |= v.x | v.y | v.z | v.w;
        }
        uint32_t ok = e ? ((andv & TAGM) == TAGM) : ((orv & TAGM) == 0u);
        if (__ballot(ok != 0u) == ~0ull) break;
        if (++spins > (1 << 16)) break;      // fail loud, never hang
      }
      __builtin_amdgcn_sched_barrier(0);     // keep MFMAs after the final waitcnt
    }

    // ---- h-part MFMAs seeded with this step's x-part ----
    f32x4 acc0 = xacc, acc1 = (f32x4){0.f,0.f,0.f,0.f};
    #pragma unroll
    for (int kt = 0; kt < 16; kt += 2) {
      acc0 = __builtin_amdgcn_mfma_f32_16x16x32_bf16(hq[kt].s,   wl[(wv*32+16+kt)*64+lane],   acc0, 0,0,0);
      acc1 = __builtin_amdgcn_mfma_f32_16x16x32_bf16(hq[kt+1].s, wl[(wv*32+16+kt+1)*64+lane], acc1, 0,0,0);
    }
    f32x4 acc = acc0 + acc1;

    // stage C tile: C/D layout col=lane&15, row=(lane>>4)*4+reg (m89-verified)
    {
      int r0 = (lane >> 4) * 4;
      c_lds[wv][r0 + 0][lane & 15] = acc[0];
      c_lds[wv][r0 + 1][lane & 15] = acc[1];
      c_lds[wv][r0 + 2][lane & 15] = acc[2];
      c_lds[wv][r0 + 3][lane & 15] = acc[3];
    }
    __syncthreads();   // only outstanding VMEM here is >=1-step-old stores: drain ~free

    // pointwise LSTM cell
    float gi = fsigmoid(c_lds[0][pb][pc] + bias0);
    float gf = fsigmoid(c_lds[1][pb][pc] + bias1);
    float gg = ftanh  (c_lds[2][pb][pc] + bias2);
    float go = fsigmoid(c_lds[3][pb][pc] + bias3);
    c_reg = gf * c_reg + gi * gg;
    float h = go * ftanh(c_reg);

    if (t < T_STEPS - 1) {
      // fire tagged h_{t+1} stores into parity pr^1 — no drain, no sentinel
      {
        float hn = __shfl_xor(h, 1);
        if (!(pc & 1)) {
          uint32_t both = (uint32_t)f2bf(h) | ((uint32_t)f2bf(hn) << 16);
          const uint32_t tagw = 1u ^ ((((uint32_t)t + 1) >> 1) & 1u);
          uint32_t v = (both & ~TAGM) | (tagw * TAGM);
          uint32_t* p = (uint32_t*)(h_buf + ((size_t)((pr ^ 1) * NGROUP + grp) * GB + pb) * DIM + colg);
          __hip_atomic_store(p, v, __ATOMIC_RELAXED, __HIP_MEMORY_SCOPE_AGENT);
        }
      }
      // off-critical-path: output store + next step's x-part (overlaps store flight)
      out[((size_t)t * BATCH + B0 + pb) * DIM + colg] = h;
      f32x4 a2_0 = (f32x4){0.f,0.f,0.f,0.f}, a2_1 = (f32x4){0.f,0.f,0.f,0.f};
      const u16* xr = xbf + (size_t)((t + 1) * BATCH + B0 + m) * DIM;
      for (int kt = 0; kt < 16; kt += 2) {
        short8 a = *((const short8*)(xr + kt * 32 + kq));
        a2_0 = __builtin_amdgcn_mfma_f32_16x16x32_bf16(a, wl[(wv*32+kt)*64+lane], a2_0, 0,0,0);
        short8 a2 = *((const short8*)(xr + (kt+1) * 32 + kq));
        a2_1 = __builtin_amdgcn_mfma_f32_16x16x32_bf16(a2, wl[(wv*32+kt+1)*64+lane], a2_1, 0,0,0);
      }
      xacc = a2_0 + a2_1;
    } else {
      out[((size_t)t * BATCH + B0 + pb) * DIM + colg] = h;
      out[TBH + (B0 + pb) * DIM + colg]      = h;
      out[TBH + BH + (B0 + pb) * DIM + colg] = c_reg;
    }
  }
}

extern "C" void kernel_launch(void* const* d_in, const int* in_sizes, int n_in,
                              void* d_out, int out_size, void* d_ws, size_t ws_size,
                              hipStream_t stream) {
  (void)in_sizes; (void)n_in; (void)out_size; (void)ws_size;
  const float* x    = (const float*)d_in[0];
  const float* h0   = (const float*)d_in[1];
  const float* c0   = (const float*)d_in[2];
  const float* w_ih = (const float*)d_in[3];
  const float* b_ih = (const float*)d_in[4];
  const float* w_hh = (const float*)d_in[5];
  const float* b_hh = (const float*)d_in[6];
  float* out = (float*)d_out;

  char* ws = (char*)d_ws;
  uint4* wpack = (uint4*)ws;                                    // 4 MiB
  u16*   xbf   = (u16*)(ws + ((size_t)4 << 20));                // 32 MiB
  u16*   hbuf  = (u16*)(ws + ((size_t)36 << 20));               // 128 KiB

  pack_w_kernel<<<dim3(32),   dim3(256), 0, stream>>>(w_ih, w_hh, wpack);
  pack_x_kernel<<<dim3(8192), dim3(256), 0, stream>>>(x, (uint4*)xbf);

  void* args[] = {(void*)&h0, (void*)&c0, (void*)&b_ih, (void*)&b_hh,
                  (void*)&wpack, (void*)&xbf, (void*)&hbuf, (void*)&out};
  hipError_t e = hipLaunchCooperativeKernel((void*)lstm_persist, dim3(NGROUP * WG_PER_GROUP),
                                            dim3(256), args, 0, stream);
  if (e != hipSuccess) {
    // fallback: 128 blocks @ 1 block/CU on 256 CUs will co-schedule
    lstm_persist<<<dim3(NGROUP * WG_PER_GROUP), dim3(256), 0, stream>>>(
        h0, c0, b_ih, b_hh, wpack, xbf, hbuf, out);
  }
}